// Round 12
// baseline (326.341 us; speedup 1.0000x reference)
//
#include <hip/hip_runtime.h>
#include <hip/hip_bf16.h>
#include <math.h>

#define Hh 32
#define Nseq 8192
#define Dh 128
#define NBd 32          // number of 256-row chunks / key blocks
#define BLKSZ 256
#define SAMP 256
#define CHK 64          // kv inner chunk
#define LOG32 3.4657359027997265f
#define SCALE 0.088388347648318447f
#define SKW 136         // K row width: 128 d + 8 pad (272B rows, 16B-aligned)
#define SVB 264         // B-kernel V^T row width: 256 keys + 8 pad

typedef float f32x4 __attribute__((ext_vector_type(4)));
typedef unsigned ui32x4 __attribute__((ext_vector_type(4)));
typedef __bf16 bf16x8 __attribute__((ext_vector_type(8)));

__device__ __forceinline__ f32x4 mfma16(bf16x8 a, bf16x8 b, f32x4 c) {
  return __builtin_amdgcn_mfma_f32_16x16x32_bf16(a, b, c, 0, 0, 0);
}

__device__ __forceinline__ bf16x8 cvt8(const float* __restrict__ p) {
  float4 a = ((const float4*)p)[0];
  float4 b = ((const float4*)p)[1];
  bf16x8 r;
  r[0] = (__bf16)a.x; r[1] = (__bf16)a.y; r[2] = (__bf16)a.z; r[3] = (__bf16)a.w;
  r[4] = (__bf16)b.x; r[5] = (__bf16)b.y; r[6] = (__bf16)b.z; r[7] = (__bf16)b.w;
  return r;
}

__device__ __forceinline__ bf16x8 cvt8v(float4 a, float4 b) {
  bf16x8 r;
  r[0] = (__bf16)a.x; r[1] = (__bf16)a.y; r[2] = (__bf16)a.z; r[3] = (__bf16)a.w;
  r[4] = (__bf16)b.x; r[5] = (__bf16)b.y; r[6] = (__bf16)b.z; r[7] = (__bf16)b.w;
  return r;
}

// round pair to bf16, return packed u32 (lo=a, hi=b) + rounded floats
__device__ __forceinline__ unsigned pack2(float a, float b, float& ra, float& rb) {
  __bf16 ba = (__bf16)a, bb = (__bf16)b;
  ra = (float)ba; rb = (float)bb;
  return ((unsigned)__builtin_bit_cast(unsigned short, bb) << 16) |
         (unsigned)__builtin_bit_cast(unsigned short, ba);
}

// ---------------- LSH hash: one thread per row, sequential fp64 ----------------
__global__ __launch_bounds__(256) void lsh_hash_kernel(
    const float* __restrict__ q, const float* __restrict__ k,
    const float* __restrict__ proj, int* __restrict__ buckets) {
  int row = blockIdx.x * 256 + threadIdx.x;          // 0 .. 2*32*8192-1
  const float* x = ((row >> 18) ? k : q) + (size_t)(row & (Hh * Nseq - 1)) * Dh;
  double acc[7] = {0, 0, 0, 0, 0, 0, 0};
#pragma unroll 8
  for (int d0 = 0; d0 < Dh; d0 += 4) {
    float4 xv = *(const float4*)(x + d0);
    double x0 = (double)xv.x, x1 = (double)xv.y, x2 = (double)xv.z, x3 = (double)xv.w;
#pragma unroll
    for (int j = 0; j < 7; j++) {
      acc[j] = fma(x0, (double)proj[(d0 + 0) * 7 + j], acc[j]);
      acc[j] = fma(x1, (double)proj[(d0 + 1) * 7 + j], acc[j]);
      acc[j] = fma(x2, (double)proj[(d0 + 2) * 7 + j], acc[j]);
      acc[j] = fma(x3, (double)proj[(d0 + 3) * 7 + j], acc[j]);
    }
  }
  int bin = 0;
#pragma unroll
  for (int j = 0; j < 7; j++) bin |= (acc[j] > 0.0 ? 1 : 0) << j;
  buckets[row] = bin ^ (bin >> 1);
}

// ---------------- stable counting sort by bucket, per (tensor, head) ----------------
__global__ __launch_bounds__(64) void bucket_sort_kernel(
    const int* __restrict__ buckets, int* __restrict__ idx) {
  __shared__ unsigned hist[64][128];
  int t = threadIdx.x;
  int base = blockIdx.x * Nseq;
  for (int b = 0; b < 128; b++) hist[t][b] = 0;
  __syncthreads();
  for (int i = 0; i < 128; i++) {
    int b = buckets[base + t * 128 + i];
    hist[t][b]++;
  }
  __syncthreads();
  int b0 = 2 * t, b1 = 2 * t + 1;
  unsigned tot0 = 0, tot1 = 0;
  for (int tt = 0; tt < 64; tt++) { unsigned h = hist[tt][b0]; hist[tt][b0] = tot0; tot0 += h; }
  for (int tt = 0; tt < 64; tt++) { unsigned h = hist[tt][b1]; hist[tt][b1] = tot1; tot1 += h; }
  unsigned pair = tot0 + tot1;
  unsigned scan = pair;
  for (int s = 1; s < 64; s <<= 1) {
    unsigned u = __shfl_up(scan, s);
    if (t >= s) scan += u;
  }
  unsigned start0 = scan - pair;
  unsigned start1 = start0 + tot0;
  __syncthreads();
  for (int tt = 0; tt < 64; tt++) { hist[tt][b0] += start0; hist[tt][b1] += start1; }
  __syncthreads();
  for (int i = 0; i < 128; i++) {
    int gi = t * 128 + i;
    int b = buckets[base + gi];
    unsigned pos = hist[t][b]++;
    idx[base + pos] = gi;
  }
}

// ---------------- A: block-diagonal attention (256 q x 256 block keys) ----------------
// R8 structure verbatim, keys = block only (no sampled, no addend), NCH=4.
// Writes normalized attn to out + lse to lse_ws (original row order).
__global__ __launch_bounds__(512, 2) void hyper_attn_blk_kernel(
    const float* __restrict__ q, const float* __restrict__ k, const float* __restrict__ v,
    const int* __restrict__ q_idx, const int* __restrict__ k_idx,
    float* __restrict__ out, float* __restrict__ lse_ws) {
  __shared__ int s_orig[BLKSZ];
  __shared__ __attribute__((aligned(16))) __bf16 s_k[2][CHK][SKW];
  __shared__ __attribute__((aligned(16))) __bf16 s_vt[2][Dh][72];

  const int c = blockIdx.x, bh = blockIdx.y;
  const int tid = threadIdx.x;
  const int w = tid >> 6, l = tid & 63;
  const int l4 = l >> 4, lm = l & 15;
  const int jk = tid >> 3, pk = tid & 7;

  if (tid < BLKSZ) s_orig[tid] = k_idx[bh * Nseq + c * BLKSZ + tid];

  bf16x8 qf[2][4];
  const int* qi = q_idx + bh * Nseq + c * BLKSZ + w * 32;
#pragma unroll
  for (int rt = 0; rt < 2; rt++) {
    int orig = qi[rt * 16 + lm];
    const float* qp = q + ((size_t)bh * Nseq + orig) * Dh + l4 * 8;
#pragma unroll
    for (int dc = 0; dc < 4; dc++) qf[rt][dc] = cvt8(qp + dc * 32);
  }

  f32x4 O[2][8];
  float mrow[2] = {-INFINITY, -INFINITY};
  float lsum[2] = {0.f, 0.f};
#pragma unroll
  for (int rt = 0; rt < 2; rt++)
#pragma unroll
    for (int dt = 0; dt < 8; dt++) { O[rt][dt][0]=0.f; O[rt][dt][1]=0.f; O[rt][dt][2]=0.f; O[rt][dt][3]=0.f; }

  __syncthreads();

  // prologue: stage chunk 0 into buffer 0
  {
    int origk = s_orig[jk];
    const float* kp = k + ((size_t)bh * Nseq + origk) * Dh + pk * 16;
    *(bf16x8*)&s_k[0][jk][pk * 16]     = cvt8(kp);
    *(bf16x8*)&s_k[0][jk][pk * 16 + 8] = cvt8(kp + 8);
    int origv = s_orig[l];
    const float* vp = v + ((size_t)bh * Nseq + origv) * Dh + w * 16;
    float4 A = ((const float4*)vp)[0], B = ((const float4*)vp)[1];
    float4 C = ((const float4*)vp)[2], Dv = ((const float4*)vp)[3];
    float tmp[16] = {A.x,A.y,A.z,A.w,B.x,B.y,B.z,B.w,C.x,C.y,C.z,C.w,Dv.x,Dv.y,Dv.z,Dv.w};
#pragma unroll
    for (int dd = 0; dd < 16; dd++) s_vt[0][w * 16 + dd][l] = (__bf16)tmp[dd];
  }
  __syncthreads();

  const int laneA = lm + 32 * (l4 & 1);
  const bool hi = (l4 >> 1) & 1;

  for (int ch = 0; ch < 4; ch++) {
    const int cur = ch & 1;
    const bool pf = (ch + 1 < 4);

    float4 kA, kB, kC, kD, vA, vB, vC, vD;
    if (pf) {
      int origk = s_orig[(ch + 1) * CHK + jk];
      const float4* kp = (const float4*)(k + ((size_t)bh * Nseq + origk) * Dh + pk * 16);
      kA = kp[0]; kB = kp[1]; kC = kp[2]; kD = kp[3];
      int origv = s_orig[(ch + 1) * CHK + l];
      const float4* vp = (const float4*)(v + ((size_t)bh * Nseq + origv) * Dh + w * 16);
      vA = vp[0]; vB = vp[1]; vC = vp[2]; vD = vp[3];
    }

    float sc[2][4][4];
#pragma unroll
    for (int ct = 0; ct < 4; ct++) {
      f32x4 acc0, acc1;
      acc0[0]=0.f;acc0[1]=0.f;acc0[2]=0.f;acc0[3]=0.f;
      acc1[0]=0.f;acc1[1]=0.f;acc1[2]=0.f;acc1[3]=0.f;
#pragma unroll
      for (int dc = 0; dc < 4; dc++) {
        bf16x8 kf = *(const bf16x8*)&s_k[cur][ct * 16 + lm][dc * 32 + l4 * 8];
        acc0 = mfma16(kf, qf[0][dc], acc0);
        acc1 = mfma16(kf, qf[1][dc], acc1);
      }
#pragma unroll
      for (int r = 0; r < 4; r++) {
        sc[0][ct][r] = acc0[r] * SCALE;
        sc[1][ct][r] = acc1[r] * SCALE;
      }
    }

    unsigned q01[2][4], q23[2][4];
#pragma unroll
    for (int rt = 0; rt < 2; rt++) {
      float mc = sc[rt][0][0];
#pragma unroll
      for (int ct = 0; ct < 4; ct++)
#pragma unroll
        for (int r = 0; r < 4; r++) mc = fmaxf(mc, sc[rt][ct][r]);
      mc = fmaxf(mc, __shfl_xor(mc, 16));
      mc = fmaxf(mc, __shfl_xor(mc, 32));
      float mn = fmaxf(mrow[rt], mc);
      float alpha = __expf(mrow[rt] - mn);
      mrow[rt] = mn;
      f32x4 aO;
#pragma unroll
      for (int r = 0; r < 4; r++) aO[r] = __shfl(alpha, l4 * 4 + r);
#pragma unroll
      for (int dt = 0; dt < 8; dt++) O[rt][dt] *= aO;
      float rsum = 0.f;
#pragma unroll
      for (int ct = 0; ct < 4; ct++) {
        float p0 = __expf(sc[rt][ct][0] - mn);
        float p1 = __expf(sc[rt][ct][1] - mn);
        float p2 = __expf(sc[rt][ct][2] - mn);
        float p3 = __expf(sc[rt][ct][3] - mn);
        float ra, rb, rc, rd;
        q01[rt][ct] = pack2(p0, p1, ra, rb);
        q23[rt][ct] = pack2(p2, p3, rc, rd);
        rsum += (ra + rb) + (rc + rd);
      }
      rsum += __shfl_xor(rsum, 16);
      rsum += __shfl_xor(rsum, 32);
      lsum[rt] = lsum[rt] * alpha + rsum;
    }

    if (pf) {
      *(bf16x8*)&s_k[cur ^ 1][jk][pk * 16]     = cvt8v(kA, kB);
      *(bf16x8*)&s_k[cur ^ 1][jk][pk * 16 + 8] = cvt8v(kC, kD);
      float ta[16] = {vA.x,vA.y,vA.z,vA.w,vB.x,vB.y,vB.z,vB.w,
                      vC.x,vC.y,vC.z,vC.w,vD.x,vD.y,vD.z,vD.w};
#pragma unroll
      for (int dd = 0; dd < 16; dd++) s_vt[cur ^ 1][w * 16 + dd][l] = (__bf16)ta[dd];
    }

#pragma unroll
    for (int kc = 0; kc < 2; kc++) {
      bf16x8 pa[2];
#pragma unroll
      for (int rt = 0; rt < 2; rt++) {
        unsigned a0 = __shfl((int)q01[rt][2 * kc],     laneA);
        unsigned b0 = __shfl((int)q01[rt][2 * kc + 1], laneA);
        unsigned a1 = __shfl((int)q23[rt][2 * kc],     laneA);
        unsigned b1 = __shfl((int)q23[rt][2 * kc + 1], laneA);
        unsigned a2 = __shfl((int)q01[rt][2 * kc],     laneA + 16);
        unsigned b2 = __shfl((int)q01[rt][2 * kc + 1], laneA + 16);
        unsigned a3 = __shfl((int)q23[rt][2 * kc],     laneA + 16);
        unsigned b3 = __shfl((int)q23[rt][2 * kc + 1], laneA + 16);
        ui32x4 pw;
        pw[0] = hi ? b0 : a0;
        pw[1] = hi ? b1 : a1;
        pw[2] = hi ? b2 : a2;
        pw[3] = hi ? b3 : a3;
        pa[rt] = __builtin_bit_cast(bf16x8, pw);
      }
#pragma unroll
      for (int dt = 0; dt < 8; dt++) {
        bf16x8 vb = *(const bf16x8*)&s_vt[cur][dt * 16 + lm][kc * 32 + l4 * 8];
        O[0][dt] = mfma16(pa[0], vb, O[0][dt]);
        O[1][dt] = mfma16(pa[1], vb, O[1][dt]);
      }
    }
    __syncthreads();
  }

  // epilogue: write normalized attn (original order) + lse
#pragma unroll
  for (int rt = 0; rt < 2; rt++) {
    float inv = 1.0f / lsum[rt];
    f32x4 invr;
#pragma unroll
    for (int r = 0; r < 4; r++) invr[r] = __shfl(inv, l4 * 4 + r);
    int orow[4];
#pragma unroll
    for (int r = 0; r < 4; r++)
      orow[r] = q_idx[bh * Nseq + c * BLKSZ + w * 32 + rt * 16 + l4 * 4 + r];
#pragma unroll
    for (int r = 0; r < 4; r++) {
      float* op = out + ((size_t)bh * Nseq + orow[r]) * Dh + lm;
#pragma unroll
      for (int dt = 0; dt < 8; dt++) op[dt * 16] = O[rt][dt][r] * invr[r];
    }
    if (l4 == 0) {
      int orow0 = q_idx[bh * Nseq + c * BLKSZ + w * 32 + rt * 16 + lm];
      lse_ws[bh * Nseq + orow0] = mrow[rt] + __logf(lsum[rt]);
    }
  }
}

// ---------------- B: residual attention + log-space combine ----------------
// WG = (head, 1024-q octant). Sampled 256 K/V staged ONCE in LDS (138KB),
// then per-wave flash with NO barriers; combines with A's output in fp32.
__global__ __launch_bounds__(512, 1) void hyper_attn_res_kernel(
    const float* __restrict__ q, const float* __restrict__ k, const float* __restrict__ v,
    const int* __restrict__ sampled, const int* __restrict__ q_idx,
    const int* __restrict__ k_idx, const float* __restrict__ lse_ws,
    float* __restrict__ out) {
  __shared__ int s_sp[SAMP];
  __shared__ __attribute__((aligned(16))) __bf16 s_k[SAMP][SKW];
  __shared__ __attribute__((aligned(16))) __bf16 s_vt[Dh][SVB];

  const int bh = blockIdx.x >> 3, oct = blockIdx.x & 7;
  const int tid = threadIdx.x;
  const int w = tid >> 6, l = tid & 63;
  const int l4 = l >> 4, lm = l & 15;
  const int jk = tid >> 3, pk = tid & 7;

  if (tid < SAMP) s_sp[tid] = sampled[bh * SAMP + tid];

  // one-time stage of all 256 sampled keys (K rows + V^T)
#pragma unroll
  for (int ps = 0; ps < 4; ps++) {
    int key = ps * 64 + jk;
    int sp = sampled[bh * SAMP + key];
    int orig = k_idx[bh * Nseq + sp];
    const float4* kp = (const float4*)(k + ((size_t)bh * Nseq + orig) * Dh + pk * 16);
    *(bf16x8*)&s_k[key][pk * 16]     = cvt8v(kp[0], kp[1]);
    *(bf16x8*)&s_k[key][pk * 16 + 8] = cvt8v(kp[2], kp[3]);
  }
#pragma unroll
  for (int ps = 0; ps < 4; ps++) {
    int key = ps * 64 + l;
    int sp = sampled[bh * SAMP + key];
    int orig = k_idx[bh * Nseq + sp];
    const float4* vp = (const float4*)(v + ((size_t)bh * Nseq + orig) * Dh + w * 16);
    float4 A = vp[0], B = vp[1], C = vp[2], Dv = vp[3];
    float tmp[16] = {A.x,A.y,A.z,A.w,B.x,B.y,B.z,B.w,C.x,C.y,C.z,C.w,Dv.x,Dv.y,Dv.z,Dv.w};
#pragma unroll
    for (int dd = 0; dd < 16; dd++) s_vt[w * 16 + dd][key] = (__bf16)tmp[dd];
  }
  __syncthreads();

  const int laneA = lm + 32 * (l4 & 1);
  const bool hi = (l4 >> 1) & 1;

  for (int t = 0; t < 4; t++) {                 // 32-row tile per wave
    const int rowb = oct * 1024 + w * 128 + t * 32;
    const int c_tile = rowb >> 8;               // q's key-block id (mask test)

    bf16x8 qf[2][4];
#pragma unroll
    for (int rt = 0; rt < 2; rt++) {
      int orig = q_idx[bh * Nseq + rowb + rt * 16 + lm];
      const float* qp = q + ((size_t)bh * Nseq + orig) * Dh + l4 * 8;
#pragma unroll
      for (int dc = 0; dc < 4; dc++) qf[rt][dc] = cvt8(qp + dc * 32);
    }

    f32x4 O[2][8];
    float mrow[2] = {-INFINITY, -INFINITY};
    float lsum[2] = {0.f, 0.f};
#pragma unroll
    for (int rt = 0; rt < 2; rt++)
#pragma unroll
      for (int dt = 0; dt < 8; dt++) { O[rt][dt][0]=0.f; O[rt][dt][1]=0.f; O[rt][dt][2]=0.f; O[rt][dt][3]=0.f; }

    for (int ch = 0; ch < 4; ch++) {            // 64 resident keys per chunk
      float sc[2][4][4];
#pragma unroll
      for (int ct = 0; ct < 4; ct++) {
        f32x4 acc0, acc1;
        acc0[0]=0.f;acc0[1]=0.f;acc0[2]=0.f;acc0[3]=0.f;
        acc1[0]=0.f;acc1[1]=0.f;acc1[2]=0.f;acc1[3]=0.f;
#pragma unroll
        for (int dc = 0; dc < 4; dc++) {
          bf16x8 kf = *(const bf16x8*)&s_k[ch * 64 + ct * 16 + lm][dc * 32 + l4 * 8];
          acc0 = mfma16(kf, qf[0][dc], acc0);
          acc1 = mfma16(kf, qf[1][dc], acc1);
        }
        ui32x4 spv = *(const ui32x4*)&s_sp[ch * 64 + ct * 16 + l4 * 4];
#pragma unroll
        for (int r = 0; r < 4; r++) {
          float add = ((((int)spv[r]) >> 8) == c_tile) ? -1e38f : LOG32;
          sc[0][ct][r] = acc0[r] * SCALE + add;
          sc[1][ct][r] = acc1[r] * SCALE + add;
        }
      }

      unsigned q01[2][4], q23[2][4];
#pragma unroll
      for (int rt = 0; rt < 2; rt++) {
        float mc = sc[rt][0][0];
#pragma unroll
        for (int ct = 0; ct < 4; ct++)
#pragma unroll
          for (int r = 0; r < 4; r++) mc = fmaxf(mc, sc[rt][ct][r]);
        mc = fmaxf(mc, __shfl_xor(mc, 16));
        mc = fmaxf(mc, __shfl_xor(mc, 32));
        float mn = fmaxf(mrow[rt], mc);
        float alpha = __expf(mrow[rt] - mn);
        mrow[rt] = mn;
        f32x4 aO;
#pragma unroll
        for (int r = 0; r < 4; r++) aO[r] = __shfl(alpha, l4 * 4 + r);
#pragma unroll
        for (int dt = 0; dt < 8; dt++) O[rt][dt] *= aO;
        float rsum = 0.f;
#pragma unroll
        for (int ct = 0; ct < 4; ct++) {
          float p0 = __expf(sc[rt][ct][0] - mn);
          float p1 = __expf(sc[rt][ct][1] - mn);
          float p2 = __expf(sc[rt][ct][2] - mn);
          float p3 = __expf(sc[rt][ct][3] - mn);
          float ra, rb, rc, rd;
          q01[rt][ct] = pack2(p0, p1, ra, rb);
          q23[rt][ct] = pack2(p2, p3, rc, rd);
          rsum += (ra + rb) + (rc + rd);
        }
        rsum += __shfl_xor(rsum, 16);
        rsum += __shfl_xor(rsum, 32);
        lsum[rt] = lsum[rt] * alpha + rsum;
      }

#pragma unroll
      for (int kc = 0; kc < 2; kc++) {
        bf16x8 pa[2];
#pragma unroll
        for (int rt = 0; rt < 2; rt++) {
          unsigned a0 = __shfl((int)q01[rt][2 * kc],     laneA);
          unsigned b0 = __shfl((int)q01[rt][2 * kc + 1], laneA);
          unsigned a1 = __shfl((int)q23[rt][2 * kc],     laneA);
          unsigned b1 = __shfl((int)q23[rt][2 * kc + 1], laneA);
          unsigned a2 = __shfl((int)q01[rt][2 * kc],     laneA + 16);
          unsigned b2 = __shfl((int)q01[rt][2 * kc + 1], laneA + 16);
          unsigned a3 = __shfl((int)q23[rt][2 * kc],     laneA + 16);
          unsigned b3 = __shfl((int)q23[rt][2 * kc + 1], laneA + 16);
          ui32x4 pw;
          pw[0] = hi ? b0 : a0;
          pw[1] = hi ? b1 : a1;
          pw[2] = hi ? b2 : a2;
          pw[3] = hi ? b3 : a3;
          pa[rt] = __builtin_bit_cast(bf16x8, pw);
        }
#pragma unroll
        for (int dt = 0; dt < 8; dt++) {
          bf16x8 vb = *(const bf16x8*)&s_vt[dt * 16 + lm][ch * 64 + kc * 32 + l4 * 8];
          O[0][dt] = mfma16(pa[0], vb, O[0][dt]);
          O[1][dt] = mfma16(pa[1], vb, O[1][dt]);
        }
      }
    }

    // combine with block estimator: softmax-weighted average in log space
#pragma unroll
    for (int rt = 0; rt < 2; rt++) {
      float lse_r = mrow[rt] + __logf(lsum[rt]);   // per lane lm (broadcast in l4)
      float inv = 1.0f / lsum[rt];
#pragma unroll
      for (int r = 0; r < 4; r++) {
        float lrr  = __shfl(lse_r, l4 * 4 + r);
        float invr = __shfl(inv,   l4 * 4 + r);
        int orow = q_idx[bh * Nseq + rowb + rt * 16 + l4 * 4 + r];
        float lb = lse_ws[bh * Nseq + orow];
        float m2 = fmaxf(lb, lrr);
        float wb = __expf(lb - m2), wr = __expf(lrr - m2);
        float sw = 1.0f / (wb + wr);
        wb *= sw; wr *= sw;
        float* op = out + ((size_t)bh * Nseq + orow) * Dh + lm;
#pragma unroll
        for (int dt = 0; dt < 8; dt++)
          op[dt * 16] = wb * op[dt * 16] + wr * (O[rt][dt][r] * invr);
      }
    }
  }
}

extern "C" void kernel_launch(void* const* d_in, const int* in_sizes, int n_in,
                              void* d_out, int out_size, void* d_ws, size_t ws_size,
                              hipStream_t stream) {
  const float* q    = (const float*)d_in[0];
  const float* k    = (const float*)d_in[1];
  const float* v    = (const float*)d_in[2];
  const float* proj = (const float*)d_in[3];
  const int* samp   = (const int*)d_in[4];
  float* out = (float*)d_out;

  int* buckets = (int*)d_ws;                   // [2][32][8192] (dead after sort)
  int* idx = buckets + 2 * Hh * Nseq;          // [2][32][8192]: q_idx, k_idx
  float* lse_ws = (float*)buckets;             // [32][8192] lse_blk (reuses buckets)

  lsh_hash_kernel<<<(2 * Hh * Nseq) / 256, 256, 0, stream>>>(q, k, proj, buckets);
  bucket_sort_kernel<<<2 * Hh, 64, 0, stream>>>(buckets, idx);
  hyper_attn_blk_kernel<<<dim3(NBd, Hh), 512, 0, stream>>>(
      q, k, v, idx /*q_idx*/, idx + Hh * Nseq /*k_idx*/, out, lse_ws);
  hyper_attn_res_kernel<<<8 * Hh, 512, 0, stream>>>(
      q, k, v, samp, idx /*q_idx*/, idx + Hh * Nseq /*k_idx*/, lse_ws, out);
}

// Round 13
// 324.435 us; speedup vs baseline: 1.0059x; 1.0059x over previous
//
#include <hip/hip_runtime.h>
#include <hip/hip_bf16.h>
#include <math.h>

#define Hh 32
#define Nseq 8192
#define Dh 128
#define NBd 32          // number of 256-row chunks / key blocks
#define BLKSZ 256
#define SAMP 256
#define KVT 512
#define CHK 64          // kv inner chunk
#define NCH 8
#define LOG32 3.4657359027997265f
#define SCALE 0.088388347648318447f
#define SKW 136         // s_k row width: 128 d + 8 pad (272B rows, 16B-aligned)
#define SVW 72          // s_vt row width: 64 keys + 8 pad (144B rows, 16B-aligned)

typedef float f32x4 __attribute__((ext_vector_type(4)));
typedef unsigned ui32x4 __attribute__((ext_vector_type(4)));
typedef __bf16 bf16x8 __attribute__((ext_vector_type(8)));

__device__ __forceinline__ f32x4 mfma16(bf16x8 a, bf16x8 b, f32x4 c) {
  return __builtin_amdgcn_mfma_f32_16x16x32_bf16(a, b, c, 0, 0, 0);
}

__device__ __forceinline__ bf16x8 cvt8(const float* __restrict__ p) {
  float4 a = ((const float4*)p)[0];
  float4 b = ((const float4*)p)[1];
  bf16x8 r;
  r[0] = (__bf16)a.x; r[1] = (__bf16)a.y; r[2] = (__bf16)a.z; r[3] = (__bf16)a.w;
  r[4] = (__bf16)b.x; r[5] = (__bf16)b.y; r[6] = (__bf16)b.z; r[7] = (__bf16)b.w;
  return r;
}

__device__ __forceinline__ bf16x8 cvt8v(float4 a, float4 b) {
  bf16x8 r;
  r[0] = (__bf16)a.x; r[1] = (__bf16)a.y; r[2] = (__bf16)a.z; r[3] = (__bf16)a.w;
  r[4] = (__bf16)b.x; r[5] = (__bf16)b.y; r[6] = (__bf16)b.z; r[7] = (__bf16)b.w;
  return r;
}

__device__ __forceinline__ unsigned pack2(float a, float b, float& ra, float& rb) {
  __bf16 ba = (__bf16)a, bb = (__bf16)b;
  ra = (float)ba; rb = (float)bb;
  return ((unsigned)__builtin_bit_cast(unsigned short, bb) << 16) |
         (unsigned)__builtin_bit_cast(unsigned short, ba);
}

// ---------------- LSH hash: one thread per row, sequential fp64 ----------------
__global__ __launch_bounds__(256) void lsh_hash_kernel(
    const float* __restrict__ q, const float* __restrict__ k,
    const float* __restrict__ proj, int* __restrict__ buckets) {
  int row = blockIdx.x * 256 + threadIdx.x;
  const float* x = ((row >> 18) ? k : q) + (size_t)(row & (Hh * Nseq - 1)) * Dh;
  double acc[7] = {0, 0, 0, 0, 0, 0, 0};
#pragma unroll 8
  for (int d0 = 0; d0 < Dh; d0 += 4) {
    float4 xv = *(const float4*)(x + d0);
    double x0 = (double)xv.x, x1 = (double)xv.y, x2 = (double)xv.z, x3 = (double)xv.w;
#pragma unroll
    for (int j = 0; j < 7; j++) {
      acc[j] = fma(x0, (double)proj[(d0 + 0) * 7 + j], acc[j]);
      acc[j] = fma(x1, (double)proj[(d0 + 1) * 7 + j], acc[j]);
      acc[j] = fma(x2, (double)proj[(d0 + 2) * 7 + j], acc[j]);
      acc[j] = fma(x3, (double)proj[(d0 + 3) * 7 + j], acc[j]);
    }
  }
  int bin = 0;
#pragma unroll
  for (int j = 0; j < 7; j++) bin |= (acc[j] > 0.0 ? 1 : 0) << j;
  buckets[row] = bin ^ (bin >> 1);
}

// ---------------- stable counting sort by bucket, per (tensor, head) ----------------
__global__ __launch_bounds__(64) void bucket_sort_kernel(
    const int* __restrict__ buckets, int* __restrict__ idx) {
  __shared__ unsigned hist[64][128];
  int t = threadIdx.x;
  int base = blockIdx.x * Nseq;
  for (int b = 0; b < 128; b++) hist[t][b] = 0;
  __syncthreads();
  for (int i = 0; i < 128; i++) {
    int b = buckets[base + t * 128 + i];
    hist[t][b]++;
  }
  __syncthreads();
  int b0 = 2 * t, b1 = 2 * t + 1;
  unsigned tot0 = 0, tot1 = 0;
  for (int tt = 0; tt < 64; tt++) { unsigned h = hist[tt][b0]; hist[tt][b0] = tot0; tot0 += h; }
  for (int tt = 0; tt < 64; tt++) { unsigned h = hist[tt][b1]; hist[tt][b1] = tot1; tot1 += h; }
  unsigned pair = tot0 + tot1;
  unsigned scan = pair;
  for (int s = 1; s < 64; s <<= 1) {
    unsigned u = __shfl_up(scan, s);
    if (t >= s) scan += u;
  }
  unsigned start0 = scan - pair;
  unsigned start1 = start0 + tot0;
  __syncthreads();
  for (int tt = 0; tt < 64; tt++) { hist[tt][b0] += start0; hist[tt][b1] += start1; }
  __syncthreads();
  for (int i = 0; i < 128; i++) {
    int gi = t * 128 + i;
    int b = buckets[base + gi];
    unsigned pos = hist[t][b]++;
    idx[base + pos] = gi;
  }
}

// ---------------- permute: materialize sorted bf16 K_s, V_t(+transpose), samp arrays ----
// grid (132, Hh), 256 thr. tile<128: 64 sorted keys -> K_s rows + V_t d-major rows.
// tile>=128: 64 sampled keys -> K_sp rows + V_sp d-major rows.
__global__ __launch_bounds__(256) void permute_kernel(
    const float* __restrict__ k, const float* __restrict__ v,
    const int* __restrict__ k_idx, const int* __restrict__ sampled,
    __bf16* __restrict__ K_s, __bf16* __restrict__ V_t,
    __bf16* __restrict__ K_sp, __bf16* __restrict__ V_sp) {
  __shared__ __attribute__((aligned(16))) __bf16 s_t[Dh][SVW];  // V^T tile
  const int tile = blockIdx.x, bh = blockIdx.y;
  const int t = threadIdx.x;
  const int j = t >> 2, seg = (t & 3) * 32;
  const bool blk = (tile < 128);
  int dpos, orig;
  if (blk) {
    dpos = tile * 64 + j;
    orig = k_idx[bh * Nseq + dpos];
  } else {
    dpos = (tile - 128) * 64 + j;
    int sp = sampled[bh * SAMP + dpos];
    orig = k_idx[bh * Nseq + sp];
  }
  // K row: gather f32, write bf16 contiguous
  {
    const float4* kp = (const float4*)(k + ((size_t)bh * Nseq + orig) * Dh + seg);
    __bf16* dst = blk ? K_s + ((size_t)bh * Nseq + dpos) * Dh + seg
                      : K_sp + ((size_t)bh * SAMP + dpos) * Dh + seg;
#pragma unroll
    for (int i = 0; i < 4; i++) *(bf16x8*)(dst + i * 8) = cvt8v(kp[2 * i], kp[2 * i + 1]);
  }
  // V row -> LDS transposed
  {
    const float4* vp = (const float4*)(v + ((size_t)bh * Nseq + orig) * Dh + seg);
#pragma unroll
    for (int i = 0; i < 8; i++) {
      float4 a = vp[i];
      s_t[seg + i * 4 + 0][j] = (__bf16)a.x;
      s_t[seg + i * 4 + 1][j] = (__bf16)a.y;
      s_t[seg + i * 4 + 2][j] = (__bf16)a.z;
      s_t[seg + i * 4 + 3][j] = (__bf16)a.w;
    }
  }
  __syncthreads();
  // read out d-rows -> V_t / V_sp (coalesced 128B per d-row)
  {
    int d = t >> 1, half = (t & 1) * 32;
    __bf16* dst = blk ? V_t + ((size_t)(bh * Dh + d)) * Nseq + tile * 64 + half
                      : V_sp + ((size_t)(bh * Dh + d)) * SAMP + (tile - 128) * 64 + half;
    const __bf16* srcp = &s_t[d][half];
#pragma unroll
    for (int i = 0; i < 4; i++) *(ui32x4*)(dst + i * 8) = *(const ui32x4*)(srcp + i * 8);
  }
}

// ---------------- fused attention, all-contiguous bf16 staging ----------------
// R8 structure verbatim (dbuf, 1 barrier/chunk, swapped QK^T, in-reg P);
// staging sources are pre-permuted bf16 arrays -> no gather, no cvt.
__global__ __launch_bounds__(512, 2) void hyper_attn_kernel(
    const float* __restrict__ q, const __bf16* __restrict__ K_s,
    const __bf16* __restrict__ V_t, const __bf16* __restrict__ K_sp,
    const __bf16* __restrict__ V_sp, const int* __restrict__ sampled,
    const int* __restrict__ q_idx, float* __restrict__ out) {
  __shared__ __attribute__((aligned(16))) float s_add[SAMP];
  __shared__ __attribute__((aligned(16))) __bf16 s_k[2][CHK][SKW];
  __shared__ __attribute__((aligned(16))) __bf16 s_vt[2][Dh][SVW];

  const int c = blockIdx.x, bh = blockIdx.y;
  const int tid = threadIdx.x;
  const int w = tid >> 6, l = tid & 63;
  const int l4 = l >> 4, lm = l & 15;
  const int jk = tid >> 3, pk = tid & 7;        // K-staging: key jk, d-seg pk*16
  const int dv = tid >> 2, ks = (tid & 3) * 16; // V-staging: d-row dv, key-seg ks

  if (tid < SAMP) {
    int sp = sampled[bh * SAMP + tid];
    s_add[tid] = ((sp >> 8) == c) ? -1e38f : LOG32;
  }

  // Q fragments (MFMA B-operand: B[d][q=lane&15]) — f32 gather, once per WG
  bf16x8 qf[2][4];
  const int* qi = q_idx + bh * Nseq + c * BLKSZ + w * 32;
#pragma unroll
  for (int rt = 0; rt < 2; rt++) {
    int orig = qi[rt * 16 + lm];
    const float* qp = q + ((size_t)bh * Nseq + orig) * Dh + l4 * 8;
#pragma unroll
    for (int dc = 0; dc < 4; dc++) qf[rt][dc] = cvt8(qp + dc * 32);
  }

  f32x4 O[2][8];
  float mrow[2] = {-INFINITY, -INFINITY};
  float lsum[2] = {0.f, 0.f};
#pragma unroll
  for (int rt = 0; rt < 2; rt++)
#pragma unroll
    for (int dt = 0; dt < 8; dt++) { O[rt][dt][0]=0.f; O[rt][dt][1]=0.f; O[rt][dt][2]=0.f; O[rt][dt][3]=0.f; }

  __syncthreads();

  // prologue: stage chunk 0 (block keys, contiguous)
  {
    const __bf16* kp = K_s + ((size_t)(bh * Nseq + c * BLKSZ) + jk) * Dh + pk * 16;
    *(ui32x4*)&s_k[0][jk][pk * 16]     = *(const ui32x4*)kp;
    *(ui32x4*)&s_k[0][jk][pk * 16 + 8] = *(const ui32x4*)(kp + 8);
    const __bf16* vp = V_t + ((size_t)(bh * Dh + dv)) * Nseq + c * BLKSZ + ks;
    *(ui32x4*)&s_vt[0][dv][ks]     = *(const ui32x4*)vp;
    *(ui32x4*)&s_vt[0][dv][ks + 8] = *(const ui32x4*)(vp + 8);
  }
  __syncthreads();

  const int laneA = lm + 32 * (l4 & 1);
  const bool hi = (l4 >> 1) & 1;

  for (int ch = 0; ch < NCH; ch++) {
    const int cur = ch & 1;
    const bool pf = (ch + 1 < NCH);

    // issue next-chunk loads (contiguous bf16; latency hides under QK+softmax)
    ui32x4 kA, kB, vA, vB;
    if (pf) {
      int cn = ch + 1;
      const __bf16* kp = (cn < 4)
          ? K_s + ((size_t)(bh * Nseq + c * BLKSZ + cn * CHK) + jk) * Dh + pk * 16
          : K_sp + ((size_t)(bh * SAMP + (cn - 4) * CHK) + jk) * Dh + pk * 16;
      kA = *(const ui32x4*)kp; kB = *(const ui32x4*)(kp + 8);
      const __bf16* vp = (cn < 4)
          ? V_t + ((size_t)(bh * Dh + dv)) * Nseq + c * BLKSZ + cn * CHK + ks
          : V_sp + ((size_t)(bh * Dh + dv)) * SAMP + (cn - 4) * CHK + ks;
      vA = *(const ui32x4*)vp; vB = *(const ui32x4*)(vp + 8);
    }

    // S^T = K·Q^T (+scale +addend): lane holds key = ch*64+ct*16+l4*4+r, q = lm
    float sc[2][4][4];
#pragma unroll
    for (int ct = 0; ct < 4; ct++) {
      f32x4 acc0, acc1;
      acc0[0]=0.f;acc0[1]=0.f;acc0[2]=0.f;acc0[3]=0.f;
      acc1[0]=0.f;acc1[1]=0.f;acc1[2]=0.f;acc1[3]=0.f;
#pragma unroll
      for (int dc = 0; dc < 4; dc++) {
        bf16x8 kf = *(const bf16x8*)&s_k[cur][ct * 16 + lm][dc * 32 + l4 * 8];
        acc0 = mfma16(kf, qf[0][dc], acc0);
        acc1 = mfma16(kf, qf[1][dc], acc1);
      }
      f32x4 addv;
      if (ch < 4) { addv[0]=0.f; addv[1]=0.f; addv[2]=0.f; addv[3]=0.f; }
      else addv = *(const f32x4*)&s_add[(ch - 4) * CHK + ct * 16 + l4 * 4];
#pragma unroll
      for (int r = 0; r < 4; r++) {
        sc[0][ct][r] = acc0[r] * SCALE + addv[r];
        sc[1][ct][r] = acc1[r] * SCALE + addv[r];
      }
    }

    // online softmax per q-row (= lane lm, replicated across l4 groups)
    unsigned q01[2][4], q23[2][4];
#pragma unroll
    for (int rt = 0; rt < 2; rt++) {
      float mc = sc[rt][0][0];
#pragma unroll
      for (int ct = 0; ct < 4; ct++)
#pragma unroll
        for (int r = 0; r < 4; r++) mc = fmaxf(mc, sc[rt][ct][r]);
      mc = fmaxf(mc, __shfl_xor(mc, 16));
      mc = fmaxf(mc, __shfl_xor(mc, 32));
      float mn = fmaxf(mrow[rt], mc);
      float alpha = __expf(mrow[rt] - mn);
      mrow[rt] = mn;
      f32x4 aO;
#pragma unroll
      for (int r = 0; r < 4; r++) aO[r] = __shfl(alpha, l4 * 4 + r);
#pragma unroll
      for (int dt = 0; dt < 8; dt++) O[rt][dt] *= aO;
      float rsum = 0.f;
#pragma unroll
      for (int ct = 0; ct < 4; ct++) {
        float p0 = __expf(sc[rt][ct][0] - mn);
        float p1 = __expf(sc[rt][ct][1] - mn);
        float p2 = __expf(sc[rt][ct][2] - mn);
        float p3 = __expf(sc[rt][ct][3] - mn);
        float ra, rb, rc, rd;
        q01[rt][ct] = pack2(p0, p1, ra, rb);
        q23[rt][ct] = pack2(p2, p3, rc, rd);
        rsum += (ra + rb) + (rc + rd);
      }
      rsum += __shfl_xor(rsum, 16);
      rsum += __shfl_xor(rsum, 32);
      lsum[rt] = lsum[rt] * alpha + rsum;
    }

    // write staged chunk ch+1 into buffer cur^1
    if (pf) {
      *(ui32x4*)&s_k[cur ^ 1][jk][pk * 16]     = kA;
      *(ui32x4*)&s_k[cur ^ 1][jk][pk * 16 + 8] = kB;
      *(ui32x4*)&s_vt[cur ^ 1][dv][ks]     = vA;
      *(ui32x4*)&s_vt[cur ^ 1][dv][ks + 8] = vB;
    }

    // PV: build A-frag P[q=lm][kc*32+l4*8+j] via packed shuffles, then MFMA
#pragma unroll
    for (int kc = 0; kc < 2; kc++) {
      bf16x8 pa[2];
#pragma unroll
      for (int rt = 0; rt < 2; rt++) {
        unsigned a0 = __shfl((int)q01[rt][2 * kc],     laneA);
        unsigned b0 = __shfl((int)q01[rt][2 * kc + 1], laneA);
        unsigned a1 = __shfl((int)q23[rt][2 * kc],     laneA);
        unsigned b1 = __shfl((int)q23[rt][2 * kc + 1], laneA);
        unsigned a2 = __shfl((int)q01[rt][2 * kc],     laneA + 16);
        unsigned b2 = __shfl((int)q01[rt][2 * kc + 1], laneA + 16);
        unsigned a3 = __shfl((int)q23[rt][2 * kc],     laneA + 16);
        unsigned b3 = __shfl((int)q23[rt][2 * kc + 1], laneA + 16);
        ui32x4 pw;
        pw[0] = hi ? b0 : a0;
        pw[1] = hi ? b1 : a1;
        pw[2] = hi ? b2 : a2;
        pw[3] = hi ? b3 : a3;
        pa[rt] = __builtin_bit_cast(bf16x8, pw);
      }
#pragma unroll
      for (int dt = 0; dt < 8; dt++) {
        bf16x8 vb = *(const bf16x8*)&s_vt[cur][dt * 16 + lm][kc * 32 + l4 * 8];
        O[0][dt] = mfma16(pa[0], vb, O[0][dt]);
        O[1][dt] = mfma16(pa[1], vb, O[1][dt]);
      }
    }
    __syncthreads();
  }

  // epilogue: normalize and scatter to original row order
#pragma unroll
  for (int rt = 0; rt < 2; rt++) {
    float inv = 1.0f / lsum[rt];
    f32x4 invr;
#pragma unroll
    for (int r = 0; r < 4; r++) invr[r] = __shfl(inv, l4 * 4 + r);
#pragma unroll
    for (int r = 0; r < 4; r++) {
      int orow = q_idx[bh * Nseq + c * BLKSZ + w * 32 + rt * 16 + l4 * 4 + r];
      float* op = out + ((size_t)bh * Nseq + orow) * Dh + lm;
#pragma unroll
      for (int dt = 0; dt < 8; dt++) op[dt * 16] = O[rt][dt][r] * invr[r];
    }
  }
}

// ---------------- fallback: R8 fused attn (f32 gather + cvt), proven 200us ----------
__global__ __launch_bounds__(512, 2) void hyper_attn_fb_kernel(
    const float* __restrict__ q, const float* __restrict__ k, const float* __restrict__ v,
    const int* __restrict__ sampled, const int* __restrict__ q_idx,
    const int* __restrict__ k_idx, float* __restrict__ out) {
  __shared__ int s_orig[KVT];
  __shared__ __attribute__((aligned(16))) float s_addf[KVT];
  __shared__ __attribute__((aligned(16))) __bf16 s_k[2][CHK][SKW];
  __shared__ __attribute__((aligned(16))) __bf16 s_vt[2][Dh][SVW];

  const int c = blockIdx.x, bh = blockIdx.y;
  const int tid = threadIdx.x;
  const int w = tid >> 6, l = tid & 63;
  const int l4 = l >> 4, lm = l & 15;
  const int jk = tid >> 3, pk = tid & 7;

  {
    int jj = tid;
    if (jj < BLKSZ) {
      s_orig[jj] = k_idx[bh * Nseq + c * BLKSZ + jj];
      s_addf[jj] = 0.0f;
    } else {
      int sp = sampled[bh * SAMP + (jj - BLKSZ)];
      s_orig[jj] = k_idx[bh * Nseq + sp];
      s_addf[jj] = ((sp >> 8) == c) ? -1e38f : LOG32;
    }
  }

  bf16x8 qf[2][4];
  const int* qi = q_idx + bh * Nseq + c * BLKSZ + w * 32;
#pragma unroll
  for (int rt = 0; rt < 2; rt++) {
    int orig = qi[rt * 16 + lm];
    const float* qp = q + ((size_t)bh * Nseq + orig) * Dh + l4 * 8;
#pragma unroll
    for (int dc = 0; dc < 4; dc++) qf[rt][dc] = cvt8(qp + dc * 32);
  }

  f32x4 O[2][8];
  float mrow[2] = {-INFINITY, -INFINITY};
  float lsum[2] = {0.f, 0.f};
#pragma unroll
  for (int rt = 0; rt < 2; rt++)
#pragma unroll
    for (int dt = 0; dt < 8; dt++) { O[rt][dt][0]=0.f; O[rt][dt][1]=0.f; O[rt][dt][2]=0.f; O[rt][dt][3]=0.f; }

  __syncthreads();

  {
    int origk = s_orig[jk];
    const float* kp = k + ((size_t)bh * Nseq + origk) * Dh + pk * 16;
    *(bf16x8*)&s_k[0][jk][pk * 16]     = cvt8(kp);
    *(bf16x8*)&s_k[0][jk][pk * 16 + 8] = cvt8(kp + 8);
    int origv = s_orig[l];
    const float* vp = v + ((size_t)bh * Nseq + origv) * Dh + w * 16;
    float4 A = ((const float4*)vp)[0], B = ((const float4*)vp)[1];
    float4 C = ((const float4*)vp)[2], Dv = ((const float4*)vp)[3];
    float tmp[16] = {A.x,A.y,A.z,A.w,B.x,B.y,B.z,B.w,C.x,C.y,C.z,C.w,Dv.x,Dv.y,Dv.z,Dv.w};
#pragma unroll
    for (int dd = 0; dd < 16; dd++) s_vt[0][w * 16 + dd][l] = (__bf16)tmp[dd];
  }
  __syncthreads();

  const int laneA = lm + 32 * (l4 & 1);
  const bool hi = (l4 >> 1) & 1;

  for (int ch = 0; ch < NCH; ch++) {
    const int cur = ch & 1;
    const bool pf = (ch + 1 < NCH);

    float4 kA, kB, kC, kD, vA, vB, vC, vD;
    if (pf) {
      int origk = s_orig[(ch + 1) * CHK + jk];
      const float4* kp = (const float4*)(k + ((size_t)bh * Nseq + origk) * Dh + pk * 16);
      kA = kp[0]; kB = kp[1]; kC = kp[2]; kD = kp[3];
      int origv = s_orig[(ch + 1) * CHK + l];
      const float4* vp = (const float4*)(v + ((size_t)bh * Nseq + origv) * Dh + w * 16);
      vA = vp[0]; vB = vp[1]; vC = vp[2]; vD = vp[3];
    }

    float sc[2][4][4];
#pragma unroll
    for (int ct = 0; ct < 4; ct++) {
      f32x4 acc0, acc1;
      acc0[0]=0.f;acc0[1]=0.f;acc0[2]=0.f;acc0[3]=0.f;
      acc1[0]=0.f;acc1[1]=0.f;acc1[2]=0.f;acc1[3]=0.f;
#pragma unroll
      for (int dc = 0; dc < 4; dc++) {
        bf16x8 kf = *(const bf16x8*)&s_k[cur][ct * 16 + lm][dc * 32 + l4 * 8];
        acc0 = mfma16(kf, qf[0][dc], acc0);
        acc1 = mfma16(kf, qf[1][dc], acc1);
      }
      f32x4 addv = *(const f32x4*)&s_addf[ch * CHK + ct * 16 + l4 * 4];
#pragma unroll
      for (int r = 0; r < 4; r++) {
        sc[0][ct][r] = acc0[r] * SCALE + addv[r];
        sc[1][ct][r] = acc1[r] * SCALE + addv[r];
      }
    }

    unsigned q01[2][4], q23[2][4];
#pragma unroll
    for (int rt = 0; rt < 2; rt++) {
      float mc = sc[rt][0][0];
#pragma unroll
      for (int ct = 0; ct < 4; ct++)
#pragma unroll
        for (int r = 0; r < 4; r++) mc = fmaxf(mc, sc[rt][ct][r]);
      mc = fmaxf(mc, __shfl_xor(mc, 16));
      mc = fmaxf(mc, __shfl_xor(mc, 32));
      float mn = fmaxf(mrow[rt], mc);
      float alpha = __expf(mrow[rt] - mn);
      mrow[rt] = mn;
      f32x4 aO;
#pragma unroll
      for (int r = 0; r < 4; r++) aO[r] = __shfl(alpha, l4 * 4 + r);
#pragma unroll
      for (int dt = 0; dt < 8; dt++) O[rt][dt] *= aO;
      float rsum = 0.f;
#pragma unroll
      for (int ct = 0; ct < 4; ct++) {
        float p0 = __expf(sc[rt][ct][0] - mn);
        float p1 = __expf(sc[rt][ct][1] - mn);
        float p2 = __expf(sc[rt][ct][2] - mn);
        float p3 = __expf(sc[rt][ct][3] - mn);
        float ra, rb, rc, rd;
        q01[rt][ct] = pack2(p0, p1, ra, rb);
        q23[rt][ct] = pack2(p2, p3, rc, rd);
        rsum += (ra + rb) + (rc + rd);
      }
      rsum += __shfl_xor(rsum, 16);
      rsum += __shfl_xor(rsum, 32);
      lsum[rt] = lsum[rt] * alpha + rsum;
    }

    if (pf) {
      *(bf16x8*)&s_k[cur ^ 1][jk][pk * 16]     = cvt8v(kA, kB);
      *(bf16x8*)&s_k[cur ^ 1][jk][pk * 16 + 8] = cvt8v(kC, kD);
      float ta[16] = {vA.x,vA.y,vA.z,vA.w,vB.x,vB.y,vB.z,vB.w,
                      vC.x,vC.y,vC.z,vC.w,vD.x,vD.y,vD.z,vD.w};
#pragma unroll
      for (int dd = 0; dd < 16; dd++) s_vt[cur ^ 1][w * 16 + dd][l] = (__bf16)ta[dd];
    }

#pragma unroll
    for (int kc = 0; kc < 2; kc++) {
      bf16x8 pa[2];
#pragma unroll
      for (int rt = 0; rt < 2; rt++) {
        unsigned a0 = __shfl((int)q01[rt][2 * kc],     laneA);
        unsigned b0 = __shfl((int)q01[rt][2 * kc + 1], laneA);
        unsigned a1 = __shfl((int)q23[rt][2 * kc],     laneA);
        unsigned b1 = __shfl((int)q23[rt][2 * kc + 1], laneA);
        unsigned a2 = __shfl((int)q01[rt][2 * kc],     laneA + 16);
        unsigned b2 = __shfl((int)q01[rt][2 * kc + 1], laneA + 16);
        unsigned a3 = __shfl((int)q23[rt][2 * kc],     laneA + 16);
        unsigned b3 = __shfl((int)q23[rt][2 * kc + 1], laneA + 16);
        ui32x4 pw;
        pw[0] = hi ? b0 : a0;
        pw[1] = hi ? b1 : a1;
        pw[2] = hi ? b2 : a2;
        pw[3] = hi ? b3 : a3;
        pa[rt] = __builtin_bit_cast(bf16x8, pw);
      }
#pragma unroll
      for (int dt = 0; dt < 8; dt++) {
        bf16x8 vb = *(const bf16x8*)&s_vt[cur][dt * 16 + lm][kc * 32 + l4 * 8];
        O[0][dt] = mfma16(pa[0], vb, O[0][dt]);
        O[1][dt] = mfma16(pa[1], vb, O[1][dt]);
      }
    }
    __syncthreads();
  }

#pragma unroll
  for (int rt = 0; rt < 2; rt++) {
    float inv = 1.0f / lsum[rt];
    f32x4 invr;
#pragma unroll
    for (int r = 0; r < 4; r++) invr[r] = __shfl(inv, l4 * 4 + r);
#pragma unroll
    for (int r = 0; r < 4; r++) {
      int orow = q_idx[bh * Nseq + c * BLKSZ + w * 32 + rt * 16 + l4 * 4 + r];
      float* op = out + ((size_t)bh * Nseq + orow) * Dh + lm;
#pragma unroll
      for (int dt = 0; dt < 8; dt++) op[dt * 16] = O[rt][dt][r] * invr[r];
    }
  }
}

extern "C" void kernel_launch(void* const* d_in, const int* in_sizes, int n_in,
                              void* d_out, int out_size, void* d_ws, size_t ws_size,
                              hipStream_t stream) {
  const float* q    = (const float*)d_in[0];
  const float* k    = (const float*)d_in[1];
  const float* v    = (const float*)d_in[2];
  const float* proj = (const float*)d_in[3];
  const int* samp   = (const int*)d_in[4];
  float* out = (float*)d_out;

  int* buckets = (int*)d_ws;                       // [2*32*8192] = 2MB
  int* idx = buckets + 2 * Hh * Nseq;              // [2*32*8192] = 2MB (q_idx, k_idx)
  __bf16* K_s  = (__bf16*)(idx + 2 * Hh * Nseq);   // 64MB
  __bf16* V_t  = K_s + (size_t)Hh * Nseq * Dh;     // 64MB
  __bf16* K_sp = V_t + (size_t)Hh * Nseq * Dh;     // 2MB
  __bf16* V_sp = K_sp + (size_t)Hh * SAMP * Dh;    // 2MB
  size_t need = (size_t)(4 * Hh * Nseq) * 4 +
                (size_t)(2 * Hh * Nseq * Dh + 2 * Hh * SAMP * Dh) * 2;

  lsh_hash_kernel<<<(2 * Hh * Nseq) / 256, 256, 0, stream>>>(q, k, proj, buckets);
  bucket_sort_kernel<<<2 * Hh, 64, 0, stream>>>(buckets, idx);
  if (ws_size >= need) {
    permute_kernel<<<dim3(132, Hh), 256, 0, stream>>>(
        k, v, idx + Hh * Nseq /*k_idx*/, samp, K_s, V_t, K_sp, V_sp);
    hyper_attn_kernel<<<dim3(NBd, Hh), 512, 0, stream>>>(
        q, K_s, V_t, K_sp, V_sp, samp, idx /*q_idx*/, out);
  } else {
    hyper_attn_fb_kernel<<<dim3(NBd, Hh), 512, 0, stream>>>(
        q, k, v, samp, idx /*q_idx*/, idx + Hh * Nseq /*k_idx*/, out);
  }
}

// Round 14
// 271.095 us; speedup vs baseline: 1.2038x; 1.1968x over previous
//
#include <hip/hip_runtime.h>
#include <hip/hip_bf16.h>
#include <math.h>

#define Hh 32
#define Nseq 8192
#define Dh 128
#define NBd 32          // number of 256-row chunks / key blocks
#define BLKSZ 256
#define SAMP 256
#define CHK 64          // kv inner chunk
#define NCH 8
#define LOG32 3.4657359027997265f
#define SCALE 0.088388347648318447f
#define SKW 136         // s_k row width: 128 d + 8 pad (272B rows, 16B-aligned)
#define SVW 72          // s_vt row width: 64 keys + 8 pad (144B rows, 16B-aligned)

typedef float f32x4 __attribute__((ext_vector_type(4)));
typedef unsigned ui32x4 __attribute__((ext_vector_type(4)));
typedef __bf16 bf16x8 __attribute__((ext_vector_type(8)));

__device__ __forceinline__ f32x4 mfma16(bf16x8 a, bf16x8 b, f32x4 c) {
  return __builtin_amdgcn_mfma_f32_16x16x32_bf16(a, b, c, 0, 0, 0);
}

__device__ __forceinline__ bf16x8 cvt8(const float* __restrict__ p) {
  float4 a = ((const float4*)p)[0];
  float4 b = ((const float4*)p)[1];
  bf16x8 r;
  r[0] = (__bf16)a.x; r[1] = (__bf16)a.y; r[2] = (__bf16)a.z; r[3] = (__bf16)a.w;
  r[4] = (__bf16)b.x; r[5] = (__bf16)b.y; r[6] = (__bf16)b.z; r[7] = (__bf16)b.w;
  return r;
}

__device__ __forceinline__ bf16x8 cvt8v(float4 a, float4 b) {
  bf16x8 r;
  r[0] = (__bf16)a.x; r[1] = (__bf16)a.y; r[2] = (__bf16)a.z; r[3] = (__bf16)a.w;
  r[4] = (__bf16)b.x; r[5] = (__bf16)b.y; r[6] = (__bf16)b.z; r[7] = (__bf16)b.w;
  return r;
}

__device__ __forceinline__ unsigned pack2(float a, float b, float& ra, float& rb) {
  __bf16 ba = (__bf16)a, bb = (__bf16)b;
  ra = (float)ba; rb = (float)bb;
  return ((unsigned)__builtin_bit_cast(unsigned short, bb) << 16) |
         (unsigned)__builtin_bit_cast(unsigned short, ba);
}

// ---------------- LSH hash: one thread per row, sequential fp64 ----------------
__global__ __launch_bounds__(256) void lsh_hash_kernel(
    const float* __restrict__ q, const float* __restrict__ k,
    const float* __restrict__ proj, int* __restrict__ buckets) {
  int row = blockIdx.x * 256 + threadIdx.x;
  const float* x = ((row >> 18) ? k : q) + (size_t)(row & (Hh * Nseq - 1)) * Dh;
  double acc[7] = {0, 0, 0, 0, 0, 0, 0};
#pragma unroll 8
  for (int d0 = 0; d0 < Dh; d0 += 4) {
    float4 xv = *(const float4*)(x + d0);
    double x0 = (double)xv.x, x1 = (double)xv.y, x2 = (double)xv.z, x3 = (double)xv.w;
#pragma unroll
    for (int j = 0; j < 7; j++) {
      acc[j] = fma(x0, (double)proj[(d0 + 0) * 7 + j], acc[j]);
      acc[j] = fma(x1, (double)proj[(d0 + 1) * 7 + j], acc[j]);
      acc[j] = fma(x2, (double)proj[(d0 + 2) * 7 + j], acc[j]);
      acc[j] = fma(x3, (double)proj[(d0 + 3) * 7 + j], acc[j]);
    }
  }
  int bin = 0;
#pragma unroll
  for (int j = 0; j < 7; j++) bin |= (acc[j] > 0.0 ? 1 : 0) << j;
  buckets[row] = bin ^ (bin >> 1);
}

// ---------------- stable counting sort by bucket, per (tensor, head) ----------------
__global__ __launch_bounds__(64) void bucket_sort_kernel(
    const int* __restrict__ buckets, int* __restrict__ idx) {
  __shared__ unsigned hist[64][128];
  int t = threadIdx.x;
  int base = blockIdx.x * Nseq;
  for (int b = 0; b < 128; b++) hist[t][b] = 0;
  __syncthreads();
  for (int i = 0; i < 128; i++) {
    int b = buckets[base + t * 128 + i];
    hist[t][b]++;
  }
  __syncthreads();
  int b0 = 2 * t, b1 = 2 * t + 1;
  unsigned tot0 = 0, tot1 = 0;
  for (int tt = 0; tt < 64; tt++) { unsigned h = hist[tt][b0]; hist[tt][b0] = tot0; tot0 += h; }
  for (int tt = 0; tt < 64; tt++) { unsigned h = hist[tt][b1]; hist[tt][b1] = tot1; tot1 += h; }
  unsigned pair = tot0 + tot1;
  unsigned scan = pair;
  for (int s = 1; s < 64; s <<= 1) {
    unsigned u = __shfl_up(scan, s);
    if (t >= s) scan += u;
  }
  unsigned start0 = scan - pair;
  unsigned start1 = start0 + tot0;
  __syncthreads();
  for (int tt = 0; tt < 64; tt++) { hist[tt][b0] += start0; hist[tt][b1] += start1; }
  __syncthreads();
  for (int i = 0; i < 128; i++) {
    int gi = t * 128 + i;
    int b = buckets[base + gi];
    unsigned pos = hist[t][b]++;
    idx[base + pos] = gi;
  }
}

// ---------------- permute sampled keys only (reused 32x per head) ----------------
// grid (4, Hh), 256 thr: 64 sampled keys/tile -> K_sp bf16 rows + V_sp d-major.
__global__ __launch_bounds__(256) void permute_samp_kernel(
    const float* __restrict__ k, const float* __restrict__ v,
    const int* __restrict__ k_idx, const int* __restrict__ sampled,
    __bf16* __restrict__ K_sp, __bf16* __restrict__ V_sp) {
  __shared__ __attribute__((aligned(16))) __bf16 s_t[Dh][SVW];
  const int tile = blockIdx.x, bh = blockIdx.y;
  const int t = threadIdx.x;
  const int j = t >> 2, seg = (t & 3) * 32;
  const int dpos = tile * 64 + j;
  const int sp = sampled[bh * SAMP + dpos];
  const int orig = k_idx[bh * Nseq + sp];
  {
    const float4* kp = (const float4*)(k + ((size_t)bh * Nseq + orig) * Dh + seg);
    __bf16* dst = K_sp + ((size_t)bh * SAMP + dpos) * Dh + seg;
#pragma unroll
    for (int i = 0; i < 4; i++) *(bf16x8*)(dst + i * 8) = cvt8v(kp[2 * i], kp[2 * i + 1]);
  }
  {
    const float4* vp = (const float4*)(v + ((size_t)bh * Nseq + orig) * Dh + seg);
#pragma unroll
    for (int i = 0; i < 8; i++) {
      float4 a = vp[i];
      s_t[seg + i * 4 + 0][j] = (__bf16)a.x;
      s_t[seg + i * 4 + 1][j] = (__bf16)a.y;
      s_t[seg + i * 4 + 2][j] = (__bf16)a.z;
      s_t[seg + i * 4 + 3][j] = (__bf16)a.w;
    }
  }
  __syncthreads();
  {
    int d = t >> 1, half = (t & 1) * 32;
    __bf16* dst = V_sp + ((size_t)(bh * Dh + d)) * SAMP + tile * 64 + half;
    const __bf16* srcp = &s_t[d][half];
#pragma unroll
    for (int i = 0; i < 4; i++) *(ui32x4*)(dst + i * 8) = *(const ui32x4*)(srcp + i * 8);
  }
}

// ---------------- fused attention: R8 structure; sampled half stages contiguous ----
__global__ __launch_bounds__(512, 2) void hyper_attn_kernel(
    const float* __restrict__ q, const float* __restrict__ k, const float* __restrict__ v,
    const __bf16* __restrict__ K_sp, const __bf16* __restrict__ V_sp,
    const int* __restrict__ sampled, const int* __restrict__ q_idx,
    const int* __restrict__ k_idx, float* __restrict__ out) {
  __shared__ int s_orig[BLKSZ];
  __shared__ __attribute__((aligned(16))) float s_add[SAMP];
  __shared__ __attribute__((aligned(16))) __bf16 s_k[2][CHK][SKW];
  __shared__ __attribute__((aligned(16))) __bf16 s_vt[2][Dh][SVW];

  const int c = blockIdx.x, bh = blockIdx.y;
  const int tid = threadIdx.x;
  const int w = tid >> 6, l = tid & 63;
  const int l4 = l >> 4, lm = l & 15;
  const int jk = tid >> 3, pk = tid & 7;        // K-staging: key jk, d-seg pk*16
  const int dv = tid >> 2, ks = (tid & 3) * 16; // contig V-staging: d-row dv, key-seg ks

  {
    int jj = tid;
    if (jj < BLKSZ) {
      s_orig[jj] = k_idx[bh * Nseq + c * BLKSZ + jj];
    } else {
      int sp = sampled[bh * SAMP + (jj - BLKSZ)];
      s_add[jj - BLKSZ] = ((sp >> 8) == c) ? -1e38f : LOG32;
    }
  }

  // Q fragments (MFMA B-operand: B[d][q=lane&15])
  bf16x8 qf[2][4];
  const int* qi = q_idx + bh * Nseq + c * BLKSZ + w * 32;
#pragma unroll
  for (int rt = 0; rt < 2; rt++) {
    int orig = qi[rt * 16 + lm];
    const float* qp = q + ((size_t)bh * Nseq + orig) * Dh + l4 * 8;
#pragma unroll
    for (int dc = 0; dc < 4; dc++) qf[rt][dc] = cvt8(qp + dc * 32);
  }

  f32x4 O[2][8];
  float mrow[2] = {-INFINITY, -INFINITY};
  float lsum[2] = {0.f, 0.f};
#pragma unroll
  for (int rt = 0; rt < 2; rt++)
#pragma unroll
    for (int dt = 0; dt < 8; dt++) { O[rt][dt][0]=0.f; O[rt][dt][1]=0.f; O[rt][dt][2]=0.f; O[rt][dt][3]=0.f; }

  __syncthreads();

  // prologue: stage chunk 0 (block keys, gather + cvt)
  {
    int origk = s_orig[jk];
    const float* kp = k + ((size_t)bh * Nseq + origk) * Dh + pk * 16;
    *(bf16x8*)&s_k[0][jk][pk * 16]     = cvt8(kp);
    *(bf16x8*)&s_k[0][jk][pk * 16 + 8] = cvt8(kp + 8);
    int origv = s_orig[l];
    const float* vp = v + ((size_t)bh * Nseq + origv) * Dh + w * 16;
    float4 A = ((const float4*)vp)[0], B = ((const float4*)vp)[1];
    float4 C = ((const float4*)vp)[2], Dv = ((const float4*)vp)[3];
    float tmp[16] = {A.x,A.y,A.z,A.w,B.x,B.y,B.z,B.w,C.x,C.y,C.z,C.w,Dv.x,Dv.y,Dv.z,Dv.w};
#pragma unroll
    for (int dd = 0; dd < 16; dd++) s_vt[0][w * 16 + dd][l] = (__bf16)tmp[dd];
  }
  __syncthreads();

  const int laneA = lm + 32 * (l4 & 1);
  const bool hi = (l4 >> 1) & 1;

  for (int ch = 0; ch < NCH; ch++) {
    const int cur = ch & 1;
    const int cn = ch + 1;
    const bool pfg = (cn < 4);               // next chunk is block keys (gather)
    const bool pfc = (cn >= 4 && cn < NCH);  // next chunk is sampled (contiguous)

    // issue next-chunk loads (latency hides under QK+softmax)
    float4 kA, kB, kC, kD, vA, vB, vC, vD;
    ui32x4 ksA, ksB, vsA, vsB;
    if (pfg) {
      int origk = s_orig[cn * CHK + jk];
      const float4* kp = (const float4*)(k + ((size_t)bh * Nseq + origk) * Dh + pk * 16);
      kA = kp[0]; kB = kp[1]; kC = kp[2]; kD = kp[3];
      int origv = s_orig[cn * CHK + l];
      const float4* vp = (const float4*)(v + ((size_t)bh * Nseq + origv) * Dh + w * 16);
      vA = vp[0]; vB = vp[1]; vC = vp[2]; vD = vp[3];
    } else if (pfc) {
      const __bf16* kp = K_sp + ((size_t)(bh * SAMP + (cn - 4) * CHK + jk)) * Dh + pk * 16;
      ksA = *(const ui32x4*)kp; ksB = *(const ui32x4*)(kp + 8);
      const __bf16* vp = V_sp + ((size_t)(bh * Dh + dv)) * SAMP + (cn - 4) * CHK + ks;
      vsA = *(const ui32x4*)vp; vsB = *(const ui32x4*)(vp + 8);
    }

    // S^T = K·Q^T (+scale +addend): lane holds key = ch*64+ct*16+l4*4+r, q = lm
    float sc[2][4][4];
#pragma unroll
    for (int ct = 0; ct < 4; ct++) {
      f32x4 acc0, acc1;
      acc0[0]=0.f;acc0[1]=0.f;acc0[2]=0.f;acc0[3]=0.f;
      acc1[0]=0.f;acc1[1]=0.f;acc1[2]=0.f;acc1[3]=0.f;
#pragma unroll
      for (int dc = 0; dc < 4; dc++) {
        bf16x8 kf = *(const bf16x8*)&s_k[cur][ct * 16 + lm][dc * 32 + l4 * 8];
        acc0 = mfma16(kf, qf[0][dc], acc0);
        acc1 = mfma16(kf, qf[1][dc], acc1);
      }
      f32x4 addv;
      if (ch < 4) { addv[0]=0.f; addv[1]=0.f; addv[2]=0.f; addv[3]=0.f; }
      else addv = *(const f32x4*)&s_add[(ch - 4) * CHK + ct * 16 + l4 * 4];
#pragma unroll
      for (int r = 0; r < 4; r++) {
        sc[0][ct][r] = acc0[r] * SCALE + addv[r];
        sc[1][ct][r] = acc1[r] * SCALE + addv[r];
      }
    }

    // online softmax per q-row (= lane lm, replicated across l4 groups)
    unsigned q01[2][4], q23[2][4];
#pragma unroll
    for (int rt = 0; rt < 2; rt++) {
      float mc = sc[rt][0][0];
#pragma unroll
      for (int ct = 0; ct < 4; ct++)
#pragma unroll
        for (int r = 0; r < 4; r++) mc = fmaxf(mc, sc[rt][ct][r]);
      mc = fmaxf(mc, __shfl_xor(mc, 16));
      mc = fmaxf(mc, __shfl_xor(mc, 32));
      float mn = fmaxf(mrow[rt], mc);
      float alpha = __expf(mrow[rt] - mn);
      mrow[rt] = mn;
      f32x4 aO;
#pragma unroll
      for (int r = 0; r < 4; r++) aO[r] = __shfl(alpha, l4 * 4 + r);
#pragma unroll
      for (int dt = 0; dt < 8; dt++) O[rt][dt] *= aO;
      float rsum = 0.f;
#pragma unroll
      for (int ct = 0; ct < 4; ct++) {
        float p0 = __expf(sc[rt][ct][0] - mn);
        float p1 = __expf(sc[rt][ct][1] - mn);
        float p2 = __expf(sc[rt][ct][2] - mn);
        float p3 = __expf(sc[rt][ct][3] - mn);
        float ra, rb, rc, rd;
        q01[rt][ct] = pack2(p0, p1, ra, rb);
        q23[rt][ct] = pack2(p2, p3, rc, rd);
        rsum += (ra + rb) + (rc + rd);
      }
      rsum += __shfl_xor(rsum, 16);
      rsum += __shfl_xor(rsum, 32);
      lsum[rt] = lsum[rt] * alpha + rsum;
    }

    // write staged chunk cn into buffer cur^1
    if (pfg) {
      *(bf16x8*)&s_k[cur ^ 1][jk][pk * 16]     = cvt8v(kA, kB);
      *(bf16x8*)&s_k[cur ^ 1][jk][pk * 16 + 8] = cvt8v(kC, kD);
      float ta[16] = {vA.x,vA.y,vA.z,vA.w,vB.x,vB.y,vB.z,vB.w,
                      vC.x,vC.y,vC.z,vC.w,vD.x,vD.y,vD.z,vD.w};
#pragma unroll
      for (int dd = 0; dd < 16; dd++) s_vt[cur ^ 1][w * 16 + dd][l] = (__bf16)ta[dd];
    } else if (pfc) {
      *(ui32x4*)&s_k[cur ^ 1][jk][pk * 16]     = ksA;
      *(ui32x4*)&s_k[cur ^ 1][jk][pk * 16 + 8] = ksB;
      *(ui32x4*)&s_vt[cur ^ 1][dv][ks]     = vsA;
      *(ui32x4*)&s_vt[cur ^ 1][dv][ks + 8] = vsB;
    }

    // PV: build A-frag P[q=lm][kc*32+l4*8+j] via packed shuffles, then MFMA
#pragma unroll
    for (int kc = 0; kc < 2; kc++) {
      bf16x8 pa[2];
#pragma unroll
      for (int rt = 0; rt < 2; rt++) {
        unsigned a0 = __shfl((int)q01[rt][2 * kc],     laneA);
        unsigned b0 = __shfl((int)q01[rt][2 * kc + 1], laneA);
        unsigned a1 = __shfl((int)q23[rt][2 * kc],     laneA);
        unsigned b1 = __shfl((int)q23[rt][2 * kc + 1], laneA);
        unsigned a2 = __shfl((int)q01[rt][2 * kc],     laneA + 16);
        unsigned b2 = __shfl((int)q01[rt][2 * kc + 1], laneA + 16);
        unsigned a3 = __shfl((int)q23[rt][2 * kc],     laneA + 16);
        unsigned b3 = __shfl((int)q23[rt][2 * kc + 1], laneA + 16);
        ui32x4 pw;
        pw[0] = hi ? b0 : a0;
        pw[1] = hi ? b1 : a1;
        pw[2] = hi ? b2 : a2;
        pw[3] = hi ? b3 : a3;
        pa[rt] = __builtin_bit_cast(bf16x8, pw);
      }
#pragma unroll
      for (int dt = 0; dt < 8; dt++) {
        bf16x8 vb = *(const bf16x8*)&s_vt[cur][dt * 16 + lm][kc * 32 + l4 * 8];
        O[0][dt] = mfma16(pa[0], vb, O[0][dt]);
        O[1][dt] = mfma16(pa[1], vb, O[1][dt]);
      }
    }
    __syncthreads();
  }

  // epilogue: normalize and scatter to original row order
#pragma unroll
  for (int rt = 0; rt < 2; rt++) {
    float inv = 1.0f / lsum[rt];
    f32x4 invr;
#pragma unroll
    for (int r = 0; r < 4; r++) invr[r] = __shfl(inv, l4 * 4 + r);
#pragma unroll
    for (int r = 0; r < 4; r++) {
      int orow = q_idx[bh * Nseq + c * BLKSZ + w * 32 + rt * 16 + l4 * 4 + r];
      float* op = out + ((size_t)bh * Nseq + orow) * Dh + lm;
#pragma unroll
      for (int dt = 0; dt < 8; dt++) op[dt * 16] = O[rt][dt][r] * invr[r];
    }
  }
}

extern "C" void kernel_launch(void* const* d_in, const int* in_sizes, int n_in,
                              void* d_out, int out_size, void* d_ws, size_t ws_size,
                              hipStream_t stream) {
  const float* q    = (const float*)d_in[0];
  const float* k    = (const float*)d_in[1];
  const float* v    = (const float*)d_in[2];
  const float* proj = (const float*)d_in[3];
  const int* samp   = (const int*)d_in[4];
  float* out = (float*)d_out;

  int* buckets = (int*)d_ws;                       // 2MB
  int* idx = buckets + 2 * Hh * Nseq;              // 2MB (q_idx, k_idx)
  __bf16* K_sp = (__bf16*)(idx + 2 * Hh * Nseq);   // 2MB [Hh][SAMP][Dh]
  __bf16* V_sp = K_sp + (size_t)Hh * SAMP * Dh;    // 2MB [Hh][Dh][SAMP]

  lsh_hash_kernel<<<(2 * Hh * Nseq) / 256, 256, 0, stream>>>(q, k, proj, buckets);
  bucket_sort_kernel<<<2 * Hh, 64, 0, stream>>>(buckets, idx);
  permute_samp_kernel<<<dim3(4, Hh), 256, 0, stream>>>(
      k, v, idx + Hh * Nseq /*k_idx*/, samp, K_sp, V_sp);
  hyper_attn_kernel<<<dim3(NBd, Hh), 512, 0, stream>>>(
      q, k, v, K_sp, V_sp, samp, idx /*q_idx*/, idx + Hh * Nseq /*k_idx*/, out);
}